// Round 9
// baseline (109.480 us; speedup 1.0000x reference)
//
#include <hip/hip_runtime.h>
#include <hip/hip_fp16.h>
#include <math.h>

// Problem constants: B=64, N=14*14*32=6272, DIN=8, D=16, M=10, C=10
#define NPOS 6272
#define DIN_ 8
#define DVEC 16
#define CCAP 10
#define JC 4                    // capsule positions per block (1 per wave)
#define NBLK (NPOS / JC)        // 1568 blocks
#define PSTRIDE 1200            // padded partial row (floats)
#define ACC_FLOATS 1194         // S[160] + T[10] + ubar[64*16]
#define P_OFF 1280              // float offset of partials in ws
#define SH_WORDS 5760           // union region: W_h2 (2560 w) / S_out 64x90 (5760 w)

// packed-fp16 dot: c += a.x*b.x + a.y*b.y (f32 accumulate)
__device__ __forceinline__ float fdot2u(unsigned a, unsigned b, float c) {
#if __has_builtin(__builtin_amdgcn_fdot2)
    typedef _Float16 h2v __attribute__((ext_vector_type(2)));
    return __builtin_amdgcn_fdot2(__builtin_bit_cast(h2v, a),
                                  __builtin_bit_cast(h2v, b), c, false);
#else
    __half2 p = __hmul2(__builtin_bit_cast(__half2, a), __builtin_bit_cast(__half2, b));
    return c + (__low2float(p) + __high2float(p));
#endif
}
__device__ __forceinline__ unsigned pack_rn(float lo, float hi) {
    return __builtin_bit_cast(unsigned, __floats2half2_rn(lo, hi));
}

// 4-lane (quad) cross-lane sums via DPP quad_perm -- pure VALU, no LDS.
__device__ __forceinline__ unsigned qsum_h2(unsigned v) {
    int t = __builtin_amdgcn_mov_dpp((int)v, 0xB1, 0xF, 0xF, true);   // xor 1
    __half2 a = __builtin_bit_cast(__half2, v);
    __half2 b = __builtin_bit_cast(__half2, (unsigned)t);
    a = __hadd2(a, b);
    v = __builtin_bit_cast(unsigned, a);
    t = __builtin_amdgcn_mov_dpp((int)v, 0x4E, 0xF, 0xF, true);        // xor 2
    b = __builtin_bit_cast(__half2, (unsigned)t);
    a = __builtin_bit_cast(__half2, v);
    a = __hadd2(a, b);
    return __builtin_bit_cast(unsigned, a);
}
__device__ __forceinline__ float qsum_f32(float v) {
    int t = __builtin_amdgcn_mov_dpp(__builtin_bit_cast(int, v), 0xB1, 0xF, 0xF, true);
    v += __builtin_bit_cast(float, t);
    t = __builtin_amdgcn_mov_dpp(__builtin_bit_cast(int, v), 0x4E, 0xF, 0xF, true);
    v += __builtin_bit_cast(float, t);
    return v;
}

// tanh(n)/n, branch-free, n >= 0. exp overflow -> rcp(inf)=0 -> tanh=1. OK.
__device__ __forceinline__ float squash_scale(float nsq) {
    float n = __builtin_amdgcn_sqrtf(nsq);
    float e = __expf(2.0f * n);
    float th = 1.0f - 2.0f * __builtin_amdgcn_rcpf(e + 1.0f);
    return th * __builtin_amdgcn_rcpf(n);
}

// ---------------------------------------------------------------------------
// Main kernel. wave = j; lane = b.
// KEY INVARIANT (r9): winner selection is invariant under the positive
// per-event squash scale sc -- argmax rounds (incl. 0-mask and -s cases) run
// on UNSQUASHED q = uraw.dc. The transcendental squash chain drops off the
// critical path; sc folds into the accumulate weights (w*sc) and ub (hfma2
// splat). Norm via fdot2(uh,uh) (8 packed ops). Zero LDS atomics; fp16 data
// movement / f32 accumulation; LDS union keeps 31.5 KB.
// ---------------------------------------------------------------------------
__global__ __launch_bounds__(256) void caps_main(
    const float* __restrict__ xin,   // [B][N][8]
    const float* __restrict__ Wg,    // [N][8][160]
    const float* __restrict__ dcg,   // [10][16]
    float* __restrict__ P,           // [NBLK][PSTRIDE] or nullptr
    float* __restrict__ ACC)         // [ACC_FLOATS] (atomic fallback)
{
    __shared__ __align__(16) unsigned SH[SH_WORDS];       // 23040 B (W_h2 / S_out union)
    __shared__ __align__(16) unsigned dch[84];            // 80 half2 words (dc)
    __shared__ __align__(16) unsigned ub_out[4][64][8];   // 8192 B

    const int tid  = threadIdx.x;
    const int lane = tid & 63;                                  // = b
    const int wvu  = __builtin_amdgcn_readfirstlane(tid >> 6);  // wave id = jj
    const int j0   = blockIdx.x * JC;
    const int j    = j0 + wvu;

    // ---- stage W as half2, i-pair interleaved: W_h2[jk][d] = (W[2k][d], W[2k+1][d]) ----
    for (int g = tid; g < 640; g += 256) {
        int jk = g / 40, d4 = g - jk * 40;      // jk = jj*4+k, d4 = d/4
        int jj = jk >> 2, k = jk & 3;
        const float* s1 = Wg + (size_t)(j0 + jj) * 1280 + (2 * k) * 160 + d4 * 4;
        float4 a = *(const float4*)s1;
        float4 b = *(const float4*)(s1 + 160);
        uint4 w;
        w.x = pack_rn(a.x, b.x); w.y = pack_rn(a.y, b.y);
        w.z = pack_rn(a.z, b.z); w.w = pack_rn(a.w, b.w);
        *(uint4*)(SH + jk * 160 + d4 * 4) = w;
    }
    // ---- stage dc as half2 (d-pairs) ----
    if (tid < 20) {
        int c = tid >> 1, part = tid & 1;
        const float4* dp = (const float4*)(dcg + c * 16 + part * 8);
        float4 a = dp[0], b = dp[1];
        uint4 w;
        w.x = pack_rn(a.x, a.y); w.y = pack_rn(a.z, a.w);
        w.z = pack_rn(b.x, b.y); w.w = pack_rn(b.z, b.w);
        *(uint4*)(dch + c * 8 + part * 4) = w;
    }

    // ---- x row (per-lane b, per-wave j) -> 4 packed half2 (i-pairs) ----
    unsigned xh[4];
    {
        const float4* xp = (const float4*)(xin + (size_t)lane * (NPOS * DIN_)
                                               + (size_t)j * DIN_);
        float4 xa = xp[0], xb = xp[1];
        xh[0] = pack_rn(xa.x, xa.y); xh[1] = pack_rn(xa.z, xa.w);
        xh[2] = pack_rn(xb.x, xb.y); xh[3] = pack_rn(xb.z, xb.w);
    }
    __syncthreads();   // staging visible to all waves

    // register accumulators
    __half2 S[CCAP][8];                 // 80 VGPRs, packed fp16 pairs (holds w*sc*uraw = w*u)
    float   T[CCAP];
    __half2 ub[8];
    #pragma unroll
    for (int c = 0; c < CCAP; ++c) {
        T[c] = 0.0f;
        #pragma unroll
        for (int k = 0; k < 8; ++k) S[c][k] = __float2half2_rn(0.0f);
    }
    #pragma unroll
    for (int k = 0; k < 8; ++k) ub[k] = __float2half2_rn(0.0f);

    const unsigned* wbase = SH + wvu * 640;

    #pragma unroll 1
    for (int m = 0; m < 10; ++m) {
        // ---- uraw[16] = x (1x8) @ W[:, m*16..+16): 16 b128 + 64 fdot2 ----
        float u[DVEC];
        #pragma unroll
        for (int d = 0; d < DVEC; ++d) u[d] = 0.0f;
        #pragma unroll
        for (int k = 0; k < 4; ++k) {
            const uint4* wk = (const uint4*)(wbase + k * 160 + m * 16);
            uint4 q0 = wk[0], q1 = wk[1], q2 = wk[2], q3 = wk[3];
            unsigned xk = xh[k];
            u[0]  = fdot2u(xk, q0.x, u[0]);  u[1]  = fdot2u(xk, q0.y, u[1]);
            u[2]  = fdot2u(xk, q0.z, u[2]);  u[3]  = fdot2u(xk, q0.w, u[3]);
            u[4]  = fdot2u(xk, q1.x, u[4]);  u[5]  = fdot2u(xk, q1.y, u[5]);
            u[6]  = fdot2u(xk, q1.z, u[6]);  u[7]  = fdot2u(xk, q1.w, u[7]);
            u[8]  = fdot2u(xk, q2.x, u[8]);  u[9]  = fdot2u(xk, q2.y, u[9]);
            u[10] = fdot2u(xk, q2.z, u[10]); u[11] = fdot2u(xk, q2.w, u[11]);
            u[12] = fdot2u(xk, q3.x, u[12]); u[13] = fdot2u(xk, q3.y, u[13]);
            u[14] = fdot2u(xk, q3.z, u[14]); u[15] = fdot2u(xk, q3.w, u[15]);
        }

        // ---- pack uraw immediately (no squash dependency) ----
        unsigned uh[8];
        #pragma unroll
        for (int k = 0; k < 8; ++k) uh[k] = pack_rn(u[2 * k], u[2 * k + 1]);

        // ---- sims q[c] = uraw.dc (scale-invariant winner input): 80 fdot2 ----
        float s[CCAP];
        #pragma unroll
        for (int c = 0; c < CCAP; ++c) {
            const uint4* dq = (const uint4*)(dch + c * 8);
            uint4 e0 = dq[0], e1 = dq[1];
            float acc = fdot2u(uh[0], e0.x, 0.0f);
            acc = fdot2u(uh[1], e0.y, acc);
            acc = fdot2u(uh[2], e0.z, acc);
            acc = fdot2u(uh[3], e0.w, acc);
            acc = fdot2u(uh[4], e1.x, acc);
            acc = fdot2u(uh[5], e1.y, acc);
            acc = fdot2u(uh[6], e1.z, acc);
            acc = fdot2u(uh[7], e1.w, acc);
            s[c] = acc;
        }

        // ---- squash scale (off the argmax critical path; scheduler overlaps) ----
        float nsq = fdot2u(uh[0], uh[0], 0.0f);
        nsq = fdot2u(uh[1], uh[1], nsq);
        nsq = fdot2u(uh[2], uh[2], nsq);
        nsq = fdot2u(uh[3], uh[3], nsq);
        float nsqb = fdot2u(uh[4], uh[4], 0.0f);
        nsqb = fdot2u(uh[5], uh[5], nsqb);
        nsqb = fdot2u(uh[6], uh[6], nsqb);
        nsqb = fdot2u(uh[7], uh[7], nsqb);
        float sc = squash_scale(nsq + nsqb);

        // ---- exact reference winner semantics (mask in {1,0,-1} bitmasks) ----
        int win0, win1, win2;
        {
            unsigned once = 0, twice = 0;
            #pragma unroll
            for (int t = 0; t < 3; ++t) {
                float best = -1e30f;
                int win = 0;
                #pragma unroll
                for (int c = 0; c < CCAP; ++c) {
                    float sv = s[c];
                    float v = (once & (1u << c)) ? ((twice & (1u << c)) ? -sv : 0.0f) : sv;
                    if (v > best) { best = v; win = c; }
                }
                twice |= (once & (1u << win));
                once  |= (1u << win);
                if (t == 0) win0 = win; else if (t == 1) win1 = win; else win2 = win;
            }
        }

        // ---- ub += sc * uraw (hfma2 splat) ----
        __half2 sch = __float2half2_rn(sc);
        #pragma unroll
        for (int k = 0; k < 8; ++k)
            ub[k] = __hfma2(sch, __builtin_bit_cast(__half2, uh[k]), ub[k]);

        // ---- dense weighted accumulate: S[c] += (w*sc) * uraw, T[c] += w ----
        #pragma unroll
        for (int c = 0; c < CCAP; ++c) {
            float w = (win0 == c ? 1.0f : 0.0f);
            w += (win1 == c) ? 0.2f : 0.0f;
            w += (win2 == c) ? 0.1f : 0.0f;
            T[c] += w;
            __half2 wh = __float2half2_rn(w * sc);
            #pragma unroll
            for (int k = 0; k < 8; ++k)
                S[c][k] = __hfma2(wh, __builtin_bit_cast(__half2, uh[k]), S[c][k]);
        }
    }

    __syncthreads();   // W region dead for ALL waves before S_out overlays it

    // ---- quad-butterfly (DPP, VALU-only) then plain LDS writes ----
    {
        unsigned sq[CCAP][8];
        float tq[CCAP];
        #pragma unroll
        for (int c = 0; c < CCAP; ++c) {
            tq[c] = qsum_f32(T[c]);
            #pragma unroll
            for (int k = 0; k < 8; ++k)
                sq[c][k] = qsum_h2(__builtin_bit_cast(unsigned, S[c][k]));
        }
        if ((lane & 3) == 0) {
            unsigned* row = SH + (wvu * 16 + (lane >> 2)) * 90;
            #pragma unroll
            for (int c = 0; c < CCAP; ++c) {
                #pragma unroll
                for (int k = 0; k < 8; ++k) row[c * 8 + k] = sq[c][k];
                row[80 + c] = __builtin_bit_cast(unsigned, tq[c]);
            }
        }
        #pragma unroll
        for (int k = 0; k < 8; ++k)
            ub_out[wvu][lane][k] = __builtin_bit_cast(unsigned, ub[k]);
    }
    __syncthreads();

    // ---- fold 64 quad-replicas + 4 ub waves, emit 1194 fp32 partials ----
    if (P != nullptr) {
        float* prow = P + (size_t)blockIdx.x * PSTRIDE;
        for (int q = tid; q < ACC_FLOATS; q += 256) {
            float v = 0.0f;
            if (q < 160) {
                int wd = (q >> 4) * 8 + ((q & 15) >> 1);
                int hi = q & 1;
                #pragma unroll 8
                for (int r = 0; r < 64; ++r) {
                    __half2 h = __builtin_bit_cast(__half2, SH[r * 90 + wd]);
                    v += hi ? __high2float(h) : __low2float(h);
                }
            } else if (q < 170) {
                #pragma unroll 8
                for (int r = 0; r < 64; ++r)
                    v += __builtin_bit_cast(float, SH[r * 90 + 80 + (q - 160)]);
            } else {
                int x = q - 170, b = x >> 4, d = x & 15;
                #pragma unroll
                for (int w2 = 0; w2 < 4; ++w2) {
                    __half2 h = __builtin_bit_cast(__half2, ub_out[w2][b][d >> 1]);
                    v += (d & 1) ? __high2float(h) : __low2float(h);
                }
            }
            prow[q] = v;
        }
    } else {
        for (int q = tid; q < ACC_FLOATS; q += 256) {
            float v = 0.0f;
            if (q < 160) {
                int wd = (q >> 4) * 8 + ((q & 15) >> 1);
                int hi = q & 1;
                #pragma unroll 8
                for (int r = 0; r < 64; ++r) {
                    __half2 h = __builtin_bit_cast(__half2, SH[r * 90 + wd]);
                    v += hi ? __high2float(h) : __low2float(h);
                }
            } else if (q < 170) {
                #pragma unroll 8
                for (int r = 0; r < 64; ++r)
                    v += __builtin_bit_cast(float, SH[r * 90 + 80 + (q - 160)]);
            } else {
                int x = q - 170, b = x >> 4, d = x & 15;
                #pragma unroll
                for (int w2 = 0; w2 < 4; ++w2) {
                    __half2 h = __builtin_bit_cast(__half2, ub_out[w2][b][d >> 1]);
                    v += (d & 1) ? __high2float(h) : __low2float(h);
                }
            }
            unsafeAtomicAdd(&ACC[q], v);
        }
    }
}

// ---------------------------------------------------------------------------
// Reduce block partials: 98 blocks x 16 rows each, atomic fold to ACC
// ---------------------------------------------------------------------------
__global__ __launch_bounds__(256) void caps_reduce(const float* __restrict__ P,
                                                   float* __restrict__ ACC)
{
    const int t = threadIdx.x;
    float acc[5] = {0.f, 0.f, 0.f, 0.f, 0.f};
    const int r0 = blockIdx.x * 16;
    for (int r = 0; r < 16; ++r) {
        const float* row = P + (size_t)(r0 + r) * PSTRIDE;
        #pragma unroll
        for (int s = 0; s < 5; ++s) {
            int col = t + 256 * s;
            float v = (col < ACC_FLOATS) ? row[col] : 0.0f;
            acc[s] += v;
        }
    }
    #pragma unroll
    for (int s = 0; s < 5; ++s) {
        int col = t + 256 * s;
        if (col < ACC_FLOATS) unsafeAtomicAdd(&ACC[col], acc[s]);
    }
}

// ---------------------------------------------------------------------------
// Finalize: dc update + row-normalize, logits = (ubar/Nm)·dc_new, softmax
// ---------------------------------------------------------------------------
__global__ __launch_bounds__(256) void caps_final(const float* __restrict__ ACC,
                                                  const float* __restrict__ dcg,
                                                  float* __restrict__ outp)
{
    __shared__ float dcn[160];
    __shared__ float rnm[10];
    __shared__ float lg[640];
    const int t = threadIdx.x;

    if (t < 160) {
        int c = t >> 4;
        float d0 = dcg[t];
        float upd = (ACC[t] - ACC[160 + c] * d0) * (float)(1.0 / 4014080.0); // /(B*N*m)
        dcn[t] = d0 + upd;
    }
    __syncthreads();
    if (t < 10) {
        float s = 0.0f;
        #pragma unroll
        for (int d = 0; d < 16; ++d) s += dcn[t * 16 + d] * dcn[t * 16 + d];
        rnm[t] = 1.0f / sqrtf(s);
    }
    __syncthreads();
    if (t < 160) dcn[t] *= rnm[t >> 4];
    __syncthreads();

    for (int q = t; q < 640; q += 256) {
        int b = q / 10, c = q - 10 * b;
        const float* ubp = &ACC[170 + b * 16];
        float s = 0.0f;
        #pragma unroll
        for (int d = 0; d < 16; ++d) s += ubp[d] * dcn[c * 16 + d];
        lg[q] = s * (float)(1.0 / 62720.0);   // mean over Nm
    }
    __syncthreads();
    if (t < 64) {
        float mx = lg[t * 10];
        #pragma unroll
        for (int c = 1; c < 10; ++c) mx = fmaxf(mx, lg[t * 10 + c]);
        float e[10];
        float ssum = 0.0f;
        #pragma unroll
        for (int c = 0; c < 10; ++c) { e[c] = expf(lg[t * 10 + c] - mx); ssum += e[c]; }
        float inv = 1.0f / ssum;
        #pragma unroll
        for (int c = 0; c < 10; ++c) outp[t * 10 + c] = e[c] * inv;
    }
}

extern "C" void kernel_launch(void* const* d_in, const int* in_sizes, int n_in,
                              void* d_out, int out_size, void* d_ws, size_t ws_size,
                              hipStream_t stream)
{
    const float* xin = (const float*)d_in[0];
    const float* Wg  = (const float*)d_in[1];
    const float* dcg = (const float*)d_in[2];
    float* outp = (float*)d_out;
    float* ws = (float*)d_ws;
    float* ACC = ws;

    const size_t need = (size_t)(P_OFF + (size_t)NBLK * PSTRIDE) * sizeof(float);
    float* P = (ws_size >= need) ? (ws + P_OFF) : nullptr;

    hipMemsetAsync(ACC, 0, ACC_FLOATS * sizeof(float), stream);
    caps_main<<<dim3(NBLK), dim3(256), 0, stream>>>(xin, Wg, dcg, P, ACC);
    if (P) caps_reduce<<<dim3(98), dim3(256), 0, stream>>>(P, ACC);
    caps_final<<<dim3(1), dim3(256), 0, stream>>>(ACC, dcg, outp);
}

// Round 10
// 105.013 us; speedup vs baseline: 1.0425x; 1.0425x over previous
//
#include <hip/hip_runtime.h>
#include <hip/hip_fp16.h>
#include <math.h>

// Problem constants: B=64, N=14*14*32=6272, DIN=8, D=16, M=10, C=10
#define NPOS 6272
#define DIN_ 8
#define DVEC 16
#define CCAP 10
#define JC 4                    // capsule positions per block (1 per wave)
#define NBLK (NPOS / JC)        // 1568 blocks
#define PSTRIDE 1200            // padded partial row (floats)
#define ACC_FLOATS 1194         // S[160] + T[10] + ubar[64*16]
#define P_OFF 1280              // float offset of partials in ws
#define SH_WORDS 5760           // union region: W_h2 (2560 w) / S_out 64x90 (5760 w)

// packed-fp16 dot: c += a.x*b.x + a.y*b.y (f32 accumulate)
__device__ __forceinline__ float fdot2u(unsigned a, unsigned b, float c) {
#if __has_builtin(__builtin_amdgcn_fdot2)
    typedef _Float16 h2v __attribute__((ext_vector_type(2)));
    return __builtin_amdgcn_fdot2(__builtin_bit_cast(h2v, a),
                                  __builtin_bit_cast(h2v, b), c, false);
#else
    __half2 p = __hmul2(__builtin_bit_cast(__half2, a), __builtin_bit_cast(__half2, b));
    return c + (__low2float(p) + __high2float(p));
#endif
}
__device__ __forceinline__ unsigned pack_rn(float lo, float hi) {
    return __builtin_bit_cast(unsigned, __floats2half2_rn(lo, hi));
}
__device__ __forceinline__ unsigned umaxu(unsigned a, unsigned b) { return a > b ? a : b; }

// 4-lane (quad) cross-lane sums via DPP quad_perm -- pure VALU, no LDS.
__device__ __forceinline__ unsigned qsum_h2(unsigned v) {
    int t = __builtin_amdgcn_mov_dpp((int)v, 0xB1, 0xF, 0xF, true);   // xor 1
    __half2 a = __builtin_bit_cast(__half2, v);
    __half2 b = __builtin_bit_cast(__half2, (unsigned)t);
    a = __hadd2(a, b);
    v = __builtin_bit_cast(unsigned, a);
    t = __builtin_amdgcn_mov_dpp((int)v, 0x4E, 0xF, 0xF, true);        // xor 2
    b = __builtin_bit_cast(__half2, (unsigned)t);
    a = __builtin_bit_cast(__half2, v);
    a = __hadd2(a, b);
    return __builtin_bit_cast(unsigned, a);
}
__device__ __forceinline__ float qsum_f32(float v) {
    int t = __builtin_amdgcn_mov_dpp(__builtin_bit_cast(int, v), 0xB1, 0xF, 0xF, true);
    v += __builtin_bit_cast(float, t);
    t = __builtin_amdgcn_mov_dpp(__builtin_bit_cast(int, v), 0x4E, 0xF, 0xF, true);
    v += __builtin_bit_cast(float, t);
    return v;
}

// tanh(n)/n, branch-free, n >= 0. exp overflow -> rcp(inf)=0 -> tanh=1. OK.
__device__ __forceinline__ float squash_scale(float nsq) {
    float n = __builtin_amdgcn_sqrtf(nsq);
    float e = __expf(2.0f * n);
    float th = 1.0f - 2.0f * __builtin_amdgcn_rcpf(e + 1.0f);
    return th * __builtin_amdgcn_rcpf(n);
}

// ---------------------------------------------------------------------------
// Main kernel. wave = j; lane = b.
// r10: ORDERED-INT PACKED ARGMAX. Sims are computed pre-biased by +64 (free:
// it's the fdot2 accumulator init), so all round values (s, 0, -s in biased
// form) are positive floats whose bit patterns order like unsigned ints.
// Low 4 mantissa bits carry (15-c) for exact first-max-on-tie semantics; a
// round is a 9-op v_max_u32 tree and "c won" is one equality vs the max.
// Replaces the ~270-op cndmask argmax (r9 showed: VALU instr count IS time).
// ---------------------------------------------------------------------------
__global__ __launch_bounds__(256) void caps_main(
    const float* __restrict__ xin,   // [B][N][8]
    const float* __restrict__ Wg,    // [N][8][160]
    const float* __restrict__ dcg,   // [10][16]
    float* __restrict__ P,           // [NBLK][PSTRIDE] or nullptr
    float* __restrict__ ACC)         // [ACC_FLOATS] (atomic fallback)
{
    __shared__ __align__(16) unsigned SH[SH_WORDS];       // 23040 B (W_h2 / S_out union)
    __shared__ __align__(16) unsigned dch[84];            // 80 half2 words (dc)
    __shared__ __align__(16) unsigned ub_out[4][64][8];   // 8192 B

    const int tid  = threadIdx.x;
    const int lane = tid & 63;                                  // = b
    const int wvu  = __builtin_amdgcn_readfirstlane(tid >> 6);  // wave id = jj
    const int j0   = blockIdx.x * JC;
    const int j    = j0 + wvu;

    // ---- stage W as half2, i-pair interleaved: W_h2[jk][d] = (W[2k][d], W[2k+1][d]) ----
    for (int g = tid; g < 640; g += 256) {
        int jk = g / 40, d4 = g - jk * 40;      // jk = jj*4+k, d4 = d/4
        int jj = jk >> 2, k = jk & 3;
        const float* s1 = Wg + (size_t)(j0 + jj) * 1280 + (2 * k) * 160 + d4 * 4;
        float4 a = *(const float4*)s1;
        float4 b = *(const float4*)(s1 + 160);
        uint4 w;
        w.x = pack_rn(a.x, b.x); w.y = pack_rn(a.y, b.y);
        w.z = pack_rn(a.z, b.z); w.w = pack_rn(a.w, b.w);
        *(uint4*)(SH + jk * 160 + d4 * 4) = w;
    }
    // ---- stage dc as half2 (d-pairs) ----
    if (tid < 20) {
        int c = tid >> 1, part = tid & 1;
        const float4* dp = (const float4*)(dcg + c * 16 + part * 8);
        float4 a = dp[0], b = dp[1];
        uint4 w;
        w.x = pack_rn(a.x, a.y); w.y = pack_rn(a.z, a.w);
        w.z = pack_rn(b.x, b.y); w.w = pack_rn(b.z, b.w);
        *(uint4*)(dch + c * 8 + part * 4) = w;
    }

    // ---- x row (per-lane b, per-wave j) -> 4 packed half2 (i-pairs) ----
    unsigned xh[4];
    {
        const float4* xp = (const float4*)(xin + (size_t)lane * (NPOS * DIN_)
                                               + (size_t)j * DIN_);
        float4 xa = xp[0], xb = xp[1];
        xh[0] = pack_rn(xa.x, xa.y); xh[1] = pack_rn(xa.z, xa.w);
        xh[2] = pack_rn(xb.x, xb.y); xh[3] = pack_rn(xb.z, xb.w);
    }
    __syncthreads();   // staging visible to all waves

    // register accumulators
    __half2 S[CCAP][8];                 // 80 VGPRs, packed fp16 pairs (holds w*sc*uraw = w*u)
    float   T[CCAP];
    __half2 ub[8];
    #pragma unroll
    for (int c = 0; c < CCAP; ++c) {
        T[c] = 0.0f;
        #pragma unroll
        for (int k = 0; k < 8; ++k) S[c][k] = __float2half2_rn(0.0f);
    }
    #pragma unroll
    for (int k = 0; k < 8; ++k) ub[k] = __float2half2_rn(0.0f);

    const unsigned* wbase = SH + wvu * 640;
    const unsigned MASKHI = 0xFFFFFFF0u;   // clears idx nibble

    #pragma unroll 1
    for (int m = 0; m < 10; ++m) {
        // ---- uraw[16] = x (1x8) @ W[:, m*16..+16): 16 b128 + 64 fdot2 ----
        float u[DVEC];
        #pragma unroll
        for (int d = 0; d < DVEC; ++d) u[d] = 0.0f;
        #pragma unroll
        for (int k = 0; k < 4; ++k) {
            const uint4* wk = (const uint4*)(wbase + k * 160 + m * 16);
            uint4 q0 = wk[0], q1 = wk[1], q2 = wk[2], q3 = wk[3];
            unsigned xk = xh[k];
            u[0]  = fdot2u(xk, q0.x, u[0]);  u[1]  = fdot2u(xk, q0.y, u[1]);
            u[2]  = fdot2u(xk, q0.z, u[2]);  u[3]  = fdot2u(xk, q0.w, u[3]);
            u[4]  = fdot2u(xk, q1.x, u[4]);  u[5]  = fdot2u(xk, q1.y, u[5]);
            u[6]  = fdot2u(xk, q1.z, u[6]);  u[7]  = fdot2u(xk, q1.w, u[7]);
            u[8]  = fdot2u(xk, q2.x, u[8]);  u[9]  = fdot2u(xk, q2.y, u[9]);
            u[10] = fdot2u(xk, q2.z, u[10]); u[11] = fdot2u(xk, q2.w, u[11]);
            u[12] = fdot2u(xk, q3.x, u[12]); u[13] = fdot2u(xk, q3.y, u[13]);
            u[14] = fdot2u(xk, q3.z, u[14]); u[15] = fdot2u(xk, q3.w, u[15]);
        }

        // ---- pack uraw immediately ----
        unsigned uh[8];
        #pragma unroll
        for (int k = 0; k < 8; ++k) uh[k] = pack_rn(u[2 * k], u[2 * k + 1]);

        // ---- BIASED sims sb[c] = uraw.dc + 64 (bias free: accumulator init) ----
        float sb[CCAP];
        #pragma unroll
        for (int c = 0; c < CCAP; ++c) {
            const uint4* dq = (const uint4*)(dch + c * 8);
            uint4 e0 = dq[0], e1 = dq[1];
            float acc = fdot2u(uh[0], e0.x, 64.0f);
            acc = fdot2u(uh[1], e0.y, acc);
            acc = fdot2u(uh[2], e0.z, acc);
            acc = fdot2u(uh[3], e0.w, acc);
            acc = fdot2u(uh[4], e1.x, acc);
            acc = fdot2u(uh[5], e1.y, acc);
            acc = fdot2u(uh[6], e1.z, acc);
            acc = fdot2u(uh[7], e1.w, acc);
            sb[c] = acc;   // = s + 64 > 0 always (|s| <~ 7 realistic max)
        }

        // ---- squash scale (independent chain; scheduler overlaps) ----
        float nsq = fdot2u(uh[0], uh[0], 0.0f);
        nsq = fdot2u(uh[1], uh[1], nsq);
        nsq = fdot2u(uh[2], uh[2], nsq);
        nsq = fdot2u(uh[3], uh[3], nsq);
        float nsqb = fdot2u(uh[4], uh[4], 0.0f);
        nsqb = fdot2u(uh[5], uh[5], nsqb);
        nsqb = fdot2u(uh[6], uh[6], nsqb);
        nsqb = fdot2u(uh[7], uh[7], nsqb);
        float sc = squash_scale(nsq + nsqb);

        // ---- ordered-int packed 3-round masked argmax ----
        // value encoding: biased positive float bits | (15-c) in low nibble.
        // round values: s -> pe, 0 -> zc (bits(64.0)|(15-c)), -s -> bits(128-sb).
        unsigned pe[CCAP], p1[CCAP], p2[CCAP];
        #pragma unroll
        for (int c = 0; c < CCAP; ++c)
            pe[c] = (__builtin_bit_cast(unsigned, sb[c]) & MASKHI) | (unsigned)(15 - c);

        unsigned m0 = pe[0];
        #pragma unroll
        for (int c = 1; c < CCAP; ++c) m0 = umaxu(m0, pe[c]);

        #pragma unroll
        for (int c = 0; c < CCAP; ++c) {
            const unsigned zc = 0x42800000u | (unsigned)(15 - c);   // bits(64.0f)|idx
            p1[c] = (pe[c] == m0) ? zc : pe[c];
        }
        unsigned m1 = p1[0];
        #pragma unroll
        for (int c = 1; c < CCAP; ++c) m1 = umaxu(m1, p1[c]);

        #pragma unroll
        for (int c = 0; c < CCAP; ++c) {
            const unsigned zc = 0x42800000u | (unsigned)(15 - c);
            unsigned ne = (__builtin_bit_cast(unsigned, 128.0f - sb[c]) & MASKHI)
                          | (unsigned)(15 - c);                     // bits(-s+64)|idx
            unsigned fresh = (m1 == zc) ? ne : zc;   // twice-chosen -> -s, else -> 0
            p2[c] = (p1[c] == m1) ? fresh : p1[c];
        }
        unsigned m2 = p2[0];
        #pragma unroll
        for (int c = 1; c < CCAP; ++c) m2 = umaxu(m2, p2[c]);

        // ---- ub += sc * uraw (hfma2 splat) ----
        __half2 sch = __float2half2_rn(sc);
        #pragma unroll
        for (int k = 0; k < 8; ++k)
            ub[k] = __hfma2(sch, __builtin_bit_cast(__half2, uh[k]), ub[k]);

        // ---- dense weighted accumulate: winner tests are equality vs round max ----
        #pragma unroll
        for (int c = 0; c < CCAP; ++c) {
            float w = (pe[c] == m0 ? 1.0f : 0.0f);
            w += (p1[c] == m1) ? 0.2f : 0.0f;
            w += (p2[c] == m2) ? 0.1f : 0.0f;
            T[c] += w;
            __half2 wh = __float2half2_rn(w * sc);
            #pragma unroll
            for (int k = 0; k < 8; ++k)
                S[c][k] = __hfma2(wh, __builtin_bit_cast(__half2, uh[k]), S[c][k]);
        }
    }

    __syncthreads();   // W region dead for ALL waves before S_out overlays it

    // ---- quad-butterfly (DPP, VALU-only) then plain LDS writes ----
    {
        unsigned sq[CCAP][8];
        float tq[CCAP];
        #pragma unroll
        for (int c = 0; c < CCAP; ++c) {
            tq[c] = qsum_f32(T[c]);
            #pragma unroll
            for (int k = 0; k < 8; ++k)
                sq[c][k] = qsum_h2(__builtin_bit_cast(unsigned, S[c][k]));
        }
        if ((lane & 3) == 0) {
            unsigned* row = SH + (wvu * 16 + (lane >> 2)) * 90;
            #pragma unroll
            for (int c = 0; c < CCAP; ++c) {
                #pragma unroll
                for (int k = 0; k < 8; ++k) row[c * 8 + k] = sq[c][k];
                row[80 + c] = __builtin_bit_cast(unsigned, tq[c]);
            }
        }
        #pragma unroll
        for (int k = 0; k < 8; ++k)
            ub_out[wvu][lane][k] = __builtin_bit_cast(unsigned, ub[k]);
    }
    __syncthreads();

    // ---- fold 64 quad-replicas + 4 ub waves, emit 1194 fp32 partials ----
    if (P != nullptr) {
        float* prow = P + (size_t)blockIdx.x * PSTRIDE;
        for (int q = tid; q < ACC_FLOATS; q += 256) {
            float v = 0.0f;
            if (q < 160) {
                int wd = (q >> 4) * 8 + ((q & 15) >> 1);
                int hi = q & 1;
                #pragma unroll 8
                for (int r = 0; r < 64; ++r) {
                    __half2 h = __builtin_bit_cast(__half2, SH[r * 90 + wd]);
                    v += hi ? __high2float(h) : __low2float(h);
                }
            } else if (q < 170) {
                #pragma unroll 8
                for (int r = 0; r < 64; ++r)
                    v += __builtin_bit_cast(float, SH[r * 90 + 80 + (q - 160)]);
            } else {
                int x = q - 170, b = x >> 4, d = x & 15;
                #pragma unroll
                for (int w2 = 0; w2 < 4; ++w2) {
                    __half2 h = __builtin_bit_cast(__half2, ub_out[w2][b][d >> 1]);
                    v += (d & 1) ? __high2float(h) : __low2float(h);
                }
            }
            prow[q] = v;
        }
    } else {
        for (int q = tid; q < ACC_FLOATS; q += 256) {
            float v = 0.0f;
            if (q < 160) {
                int wd = (q >> 4) * 8 + ((q & 15) >> 1);
                int hi = q & 1;
                #pragma unroll 8
                for (int r = 0; r < 64; ++r) {
                    __half2 h = __builtin_bit_cast(__half2, SH[r * 90 + wd]);
                    v += hi ? __high2float(h) : __low2float(h);
                }
            } else if (q < 170) {
                #pragma unroll 8
                for (int r = 0; r < 64; ++r)
                    v += __builtin_bit_cast(float, SH[r * 90 + 80 + (q - 160)]);
            } else {
                int x = q - 170, b = x >> 4, d = x & 15;
                #pragma unroll
                for (int w2 = 0; w2 < 4; ++w2) {
                    __half2 h = __builtin_bit_cast(__half2, ub_out[w2][b][d >> 1]);
                    v += (d & 1) ? __high2float(h) : __low2float(h);
                }
            }
            unsafeAtomicAdd(&ACC[q], v);
        }
    }
}

// ---------------------------------------------------------------------------
// Reduce block partials: 98 blocks x 16 rows each, atomic fold to ACC
// ---------------------------------------------------------------------------
__global__ __launch_bounds__(256) void caps_reduce(const float* __restrict__ P,
                                                   float* __restrict__ ACC)
{
    const int t = threadIdx.x;
    float acc[5] = {0.f, 0.f, 0.f, 0.f, 0.f};
    const int r0 = blockIdx.x * 16;
    for (int r = 0; r < 16; ++r) {
        const float* row = P + (size_t)(r0 + r) * PSTRIDE;
        #pragma unroll
        for (int s = 0; s < 5; ++s) {
            int col = t + 256 * s;
            float v = (col < ACC_FLOATS) ? row[col] : 0.0f;
            acc[s] += v;
        }
    }
    #pragma unroll
    for (int s = 0; s < 5; ++s) {
        int col = t + 256 * s;
        if (col < ACC_FLOATS) unsafeAtomicAdd(&ACC[col], acc[s]);
    }
}

// ---------------------------------------------------------------------------
// Finalize: dc update + row-normalize, logits = (ubar/Nm)·dc_new, softmax
// ---------------------------------------------------------------------------
__global__ __launch_bounds__(256) void caps_final(const float* __restrict__ ACC,
                                                  const float* __restrict__ dcg,
                                                  float* __restrict__ outp)
{
    __shared__ float dcn[160];
    __shared__ float rnm[10];
    __shared__ float lg[640];
    const int t = threadIdx.x;

    if (t < 160) {
        int c = t >> 4;
        float d0 = dcg[t];
        float upd = (ACC[t] - ACC[160 + c] * d0) * (float)(1.0 / 4014080.0); // /(B*N*m)
        dcn[t] = d0 + upd;
    }
    __syncthreads();
    if (t < 10) {
        float s = 0.0f;
        #pragma unroll
        for (int d = 0; d < 16; ++d) s += dcn[t * 16 + d] * dcn[t * 16 + d];
        rnm[t] = 1.0f / sqrtf(s);
    }
    __syncthreads();
    if (t < 160) dcn[t] *= rnm[t >> 4];
    __syncthreads();

    for (int q = t; q < 640; q += 256) {
        int b = q / 10, c = q - 10 * b;
        const float* ubp = &ACC[170 + b * 16];
        float s = 0.0f;
        #pragma unroll
        for (int d = 0; d < 16; ++d) s += ubp[d] * dcn[c * 16 + d];
        lg[q] = s * (float)(1.0 / 62720.0);   // mean over Nm
    }
    __syncthreads();
    if (t < 64) {
        float mx = lg[t * 10];
        #pragma unroll
        for (int c = 1; c < 10; ++c) mx = fmaxf(mx, lg[t * 10 + c]);
        float e[10];
        float ssum = 0.0f;
        #pragma unroll
        for (int c = 0; c < 10; ++c) { e[c] = expf(lg[t * 10 + c] - mx); ssum += e[c]; }
        float inv = 1.0f / ssum;
        #pragma unroll
        for (int c = 0; c < 10; ++c) outp[t * 10 + c] = e[c] * inv;
    }
}

extern "C" void kernel_launch(void* const* d_in, const int* in_sizes, int n_in,
                              void* d_out, int out_size, void* d_ws, size_t ws_size,
                              hipStream_t stream)
{
    const float* xin = (const float*)d_in[0];
    const float* Wg  = (const float*)d_in[1];
    const float* dcg = (const float*)d_in[2];
    float* outp = (float*)d_out;
    float* ws = (float*)d_ws;
    float* ACC = ws;

    const size_t need = (size_t)(P_OFF + (size_t)NBLK * PSTRIDE) * sizeof(float);
    float* P = (ws_size >= need) ? (ws + P_OFF) : nullptr;

    hipMemsetAsync(ACC, 0, ACC_FLOATS * sizeof(float), stream);
    caps_main<<<dim3(NBLK), dim3(256), 0, stream>>>(xin, Wg, dcg, P, ACC);
    if (P) caps_reduce<<<dim3(98), dim3(256), 0, stream>>>(P, ACC);
    caps_final<<<dim3(1), dim3(256), 0, stream>>>(ACC, dcg, outp);
}